// Round 11
// baseline (360.768 us; speedup 1.0000x reference)
//
#include <hip/hip_runtime.h>
#include <hip/hip_bf16.h>
#include <math.h>

#define LRELU_SLOPE 0.2f
#define EPS 1e-16f
#define BUCK_SHIFT 7
#define BUCK_NODES 128
#define MAXBUCK 1024

typedef __hip_bfloat16 bf16;
typedef __attribute__((ext_vector_type(8))) short bf16x8;
typedef __attribute__((ext_vector_type(4))) float f32x4;

__device__ inline float lrelu(float v) { return v > 0.f ? v : LRELU_SLOPE * v; }
__device__ inline float bflo(unsigned u) { return __uint_as_float(u << 16); }
__device__ inline float bfhi(unsigned u) { return __uint_as_float(u & 0xffff0000u); }
__device__ inline short f2bf(float f) {
  bf16 t = __float2bfloat16(f);
  return *reinterpret_cast<short*>(&t);
}
__device__ inline unsigned pack2(float lo, float hi) {
  return ((unsigned)(unsigned short)f2bf(hi) << 16) | (unsigned)(unsigned short)f2bf(lo);
}

// ---------------- prep: W f32 -> bf16 + zero gcur ----------------
__global__ void prep_kernel(const float* __restrict__ W2, unsigned short* __restrict__ Wb2,
                            const float* __restrict__ W1, unsigned short* __restrict__ Wb1,
                            int* __restrict__ gcur, int ngc) {
  int idx = blockIdx.x * blockDim.x + threadIdx.x;
  if (idx < ngc) gcur[idx] = 0;
  if (idx < 16384) {
    Wb2[idx] = (unsigned short)f2bf(W2[idx]);
  } else {
    int i = idx - 16384;
    if (i < 8192) Wb1[i] = (unsigned short)f2bf(W1[i]);
  }
}

// ---------------- bucket partition BOTH layers: edges -> per-bucket slabs (s<<7|d7) -------
template <int EPB>
__global__ __launch_bounds__(256) void partition_both_kernel(
    const int* __restrict__ ei2, int E2, int* __restrict__ gcur2, int* __restrict__ slab2,
    const int* __restrict__ ei1, int E1, int* __restrict__ gcur1, int* __restrict__ slab1,
    int cap, int nbuck, int nblk2) {
  __shared__ int cnt[MAXBUCK];
  __shared__ int sbase[MAXBUCK];
  const int tid = threadIdx.x;
  const bool l2 = (int)blockIdx.x < nblk2;
  const int bid = l2 ? blockIdx.x : blockIdx.x - nblk2;
  const int* ei = l2 ? ei2 : ei1;
  const int E = l2 ? E2 : E1;
  int* gcur = l2 ? gcur2 : gcur1;
  int* part = l2 ? slab2 : slab1;
  for (int t = tid; t < nbuck; t += 256) cnt[t] = 0;
  __syncthreads();
  const int e0 = bid * EPB;
  constexpr int KPT = EPB / 256;
  int sv[KPT], dv[KPT];
#pragma unroll
  for (int k = 0; k < KPT; k++) {
    int e = e0 + tid + k * 256;
    if (e < E) {
      sv[k] = ei[e];
      dv[k] = ei[E + e];
      atomicAdd(&cnt[dv[k] >> BUCK_SHIFT], 1);
    } else {
      dv[k] = -1;
    }
  }
  __syncthreads();
  for (int t = tid; t < nbuck; t += 256) {
    int c = cnt[t];
    if (c) sbase[t] = atomicAdd(&gcur[t], c);
    cnt[t] = 0;
  }
  __syncthreads();
#pragma unroll
  for (int k = 0; k < KPT; k++) {
    if (dv[k] >= 0) {
      int b = dv[k] >> BUCK_SHIFT;
      int pos = sbase[b] + atomicAdd(&cnt[b], 1);
      if (pos < cap) part[(size_t)b * cap + pos] = (sv[k] << BUCK_SHIFT) | (dv[k] & (BUCK_NODES - 1));
    }
  }
}

// ---------------- MFMA GEMM (h = x @ W^T, bf16) + fused att dots + self-loop p ------------
template <int M, int H, bool SPLIT, typename Tin>
__global__ __launch_bounds__(256) void gemm_att_mfma(
    const Tin* __restrict__ x, const unsigned short* __restrict__ Wb,
    const float* __restrict__ atts, const float* __restrict__ attd, bf16* __restrict__ h,
    float* __restrict__ asrc, float* __restrict__ adst, float* __restrict__ pself, int N) {
  constexpr int K = 128;
  constexpr int NF = M / 16;
  const int wid = threadIdx.x >> 6;
  const int lane = threadIdx.x & 63;
  const int r0 = blockIdx.x * 64 + wid * 16;
  if (r0 >= N) return;
  const int colb = lane & 15;
  const int kgrp = lane >> 4;
  const size_t arow = (size_t)min(r0 + colb, N - 1);

  f32x4 acc[NF];
#pragma unroll
  for (int f = 0; f < NF; f++) acc[f] = (f32x4){0.f, 0.f, 0.f, 0.f};

#pragma unroll
  for (int k0 = 0; k0 < K; k0 += 32) {
    const int kb = k0 + kgrp * 8;
    bf16x8 ahi, alo;
    if constexpr (SPLIT) {
      const float* xp = (const float*)x + arow * K + kb;
      float4 l0 = *(const float4*)xp;
      float4 l1 = *(const float4*)(xp + 4);
      float xv[8] = {l0.x, l0.y, l0.z, l0.w, l1.x, l1.y, l1.z, l1.w};
#pragma unroll
      for (int j = 0; j < 8; j++) {
        short hb = f2bf(xv[j]);
        ahi[j] = hb;
        float hf = __uint_as_float(((unsigned)(unsigned short)hb) << 16);
        alo[j] = f2bf(xv[j] - hf);
      }
    } else {
      ahi = *(const bf16x8*)((const unsigned short*)x + arow * K + kb);
    }
#pragma unroll
    for (int f = 0; f < NF; f++) {
      bf16x8 b = *(const bf16x8*)(Wb + (size_t)(f * 16 + colb) * K + kb);
      if constexpr (SPLIT)
        acc[f] = __builtin_amdgcn_mfma_f32_16x16x32_bf16(alo, b, acc[f], 0, 0, 0);
      acc[f] = __builtin_amdgcn_mfma_f32_16x16x32_bf16(ahi, b, acc[f], 0, 0, 0);
    }
  }

#pragma unroll
  for (int r = 0; r < 4; r++) {
    const int row = r0 + kgrp * 4 + r;
    const bool ok = row < N;
    float s0 = 0.f, d0 = 0.f, s1 = 0.f, d1 = 0.f;
#pragma unroll
    for (int f = 0; f < NF; f++) {
      float v = acc[f][r];
      int c = f * 16 + colb;
      if (ok) h[(size_t)row * M + c] = __float2bfloat16(v);
      float av = atts[c], dv = attd[c];
      if (H == 2 && f >= NF / 2) {
        s1 += v * av;
        d1 += v * dv;
      } else {
        s0 += v * av;
        d0 += v * dv;
      }
    }
#pragma unroll
    for (int off = 1; off < 16; off <<= 1) {
      s0 += __shfl_xor(s0, off);
      d0 += __shfl_xor(d0, off);
      if (H == 2) {
        s1 += __shfl_xor(s1, off);
        d1 += __shfl_xor(d1, off);
      }
    }
    if (ok && colb == 0) {
      if (H == 2) {
        asrc[2 * (size_t)row] = s0;
        asrc[2 * (size_t)row + 1] = s1;
        adst[2 * (size_t)row] = d0;
        adst[2 * (size_t)row + 1] = d1;
        *(float2*)&pself[2 * (size_t)row] =
            make_float2(__expf(lrelu(s0 + d0)), __expf(lrelu(s1 + d1)));
      } else {
        asrc[row] = s0;
        adst[row] = d0;
        pself[row] = __expf(lrelu(s0 + d0));
      }
    }
  }
}

// ---------------- FUSED per-bucket CSR build + gather --------------------------------------
// Phase A: stage slab in LDS, histogram+scan (pad-to-8), scatter eidx (in-place) + pcsr.
// Phase B (same block, after __syncthreads): gather its bucket's nodes with the proven
// quarter-wave inner loop; eidx/pcsr reads are L2-warm (written by this CU moments ago).
template <int H, typename TOut>
__global__ __launch_bounds__(256) void csr_gather_kernel(
    int* __restrict__ slab, const int* __restrict__ gcur, int cap,
    const float* __restrict__ asrc, const float* __restrict__ adst,
    const float* __restrict__ pself, float* __restrict__ pcsr, const bf16* __restrict__ h,
    const float* __restrict__ bias, TOut* __restrict__ outp, int N) {
  extern __shared__ char smem[];
  int* s_sd = (int*)smem;              // [cap] packed (s<<7|d7)
  int* hist = (int*)(s_sd + cap);      // [256] (only [0,128) used)
  int* histp = hist + 256;             // [256]
  int* escanp = histp + 256;           // [256]
  int* cur = escanp + 256;             // [256]
  int* wtot = cur + 256;               // [4]
  float* s_ad = (float*)(wtot + 4);    // [H*128]

  const int b = blockIdx.x;
  const int tid = threadIdx.x;
  const int lane = tid & 63;
  const int wid = tid >> 6;
  const int nb0 = b << BUCK_SHIFT;
  const int nn = min(BUCK_NODES, N - nb0);
  const int cnt = min(gcur[b], cap - 7 * BUCK_NODES);
  const int B = b * cap;
  int* eidx = slab;  // in-place: all slab reads staged to LDS before writes

  // ---- phase A ----
  hist[tid] = 0;
  cur[tid] = 0;
  for (int t = tid; t < nn * H; t += 256) s_ad[t] = adst[(size_t)nb0 * H + t];
  __syncthreads();
  for (int i = tid; i < cnt; i += 256) {
    int pr = slab[(size_t)B + i];
    s_sd[i] = pr;
    atomicAdd(&hist[pr & (BUCK_NODES - 1)], 1);
  }
  __syncthreads();
  const int h0 = hist[tid];
  const int hp = (h0 + 7) & ~7;
  histp[tid] = hp;
  int inc = hp;
#pragma unroll
  for (int off = 1; off < 64; off <<= 1) {
    int t = __shfl_up(inc, off);
    if (lane >= off) inc += t;
  }
  if (lane == 63) wtot[wid] = inc;
  __syncthreads();
  int base = 0;
  for (int w = 0; w < wid; w++) base += wtot[w];
  escanp[tid] = inc + base;
  __syncthreads();
  for (int i = tid; i < cnt; i += 256) {
    int pr = s_sd[i];
    int d7 = pr & (BUCK_NODES - 1);
    int s = pr >> BUCK_SHIFT;
    int slot = B + (escanp[d7] - histp[d7]) + atomicAdd(&cur[d7], 1);
    eidx[slot] = s;
    if constexpr (H == 2) {
      float2 a = *(const float2*)&asrc[2 * (size_t)s];
      float2 ad = *(const float2*)&s_ad[2 * d7];
      float2 pv;
      pv.x = __expf(lrelu(a.x + ad.x));
      pv.y = __expf(lrelu(a.y + ad.y));
      *(float2*)&pcsr[2 * (size_t)slot] = pv;
    } else {
      pcsr[slot] = __expf(lrelu(asrc[s] + s_ad[d7]));
    }
  }
  if (tid < nn) {
    int pb = B + escanp[tid] - histp[tid];
    for (int k = h0; k < hp; k++) {
      eidx[pb + k] = nb0 + tid;
      if constexpr (H == 2) {
        *(float2*)&pcsr[2 * (size_t)(pb + k)] = make_float2(0.f, 0.f);
      } else {
        pcsr[pb + k] = 0.f;
      }
    }
  }
  __syncthreads();  // global writes by this block now visible to it

  // ---- phase B: quarter-wave gather over this bucket's nodes ----
  const int qw = lane >> 4;
  const int cl = lane & 15;
  if constexpr (H == 2) {
    const bool head0 = cl < 8;
    for (int ln = wid; ln < nn; ln += 4) {
      const int n = nb0 + ln;
      const int start = B + escanp[ln] - histp[ln];
      const int end = B + escanp[ln];
      const float2 ps = *(const float2*)&pself[2 * (size_t)n];
      float g = qw ? 0.f : (head0 ? ps.x : ps.y);
      uint4 hv = *(const uint4*)&h[(size_t)n * 128 + 8 * cl];
      float den = g;
      float a0 = g * bflo(hv.x), a1 = g * bfhi(hv.x);
      float a2 = g * bflo(hv.y), a3 = g * bfhi(hv.y);
      float a4 = g * bflo(hv.z), a5 = g * bfhi(hv.z);
      float a6 = g * bflo(hv.w), a7 = g * bfhi(hv.w);
      for (int j = start + 4 * qw; j < end; j += 16) {
        int4 ia = *(const int4*)&eidx[j];
        float4 q0 = *(const float4*)&pcsr[2 * (size_t)j];
        float4 q1 = *(const float4*)&pcsr[2 * (size_t)j + 4];
        uint4 hA = *(const uint4*)&h[(size_t)ia.x * 128 + 8 * cl];
        uint4 hB = *(const uint4*)&h[(size_t)ia.y * 128 + 8 * cl];
        uint4 hC = *(const uint4*)&h[(size_t)ia.z * 128 + 8 * cl];
        uint4 hD = *(const uint4*)&h[(size_t)ia.w * 128 + 8 * cl];
        float pa = head0 ? q0.x : q0.y;
        float pb = head0 ? q0.z : q0.w;
        float pc = head0 ? q1.x : q1.y;
        float pd = head0 ? q1.z : q1.w;
        den += (pa + pb) + (pc + pd);
        a0 += (pa * bflo(hA.x) + pb * bflo(hB.x)) + (pc * bflo(hC.x) + pd * bflo(hD.x));
        a1 += (pa * bfhi(hA.x) + pb * bfhi(hB.x)) + (pc * bfhi(hC.x) + pd * bfhi(hD.x));
        a2 += (pa * bflo(hA.y) + pb * bflo(hB.y)) + (pc * bflo(hC.y) + pd * bflo(hD.y));
        a3 += (pa * bfhi(hA.y) + pb * bfhi(hB.y)) + (pc * bfhi(hC.y) + pd * bfhi(hD.y));
        a4 += (pa * bflo(hA.z) + pb * bflo(hB.z)) + (pc * bflo(hC.z) + pd * bflo(hD.z));
        a5 += (pa * bfhi(hA.z) + pb * bfhi(hB.z)) + (pc * bfhi(hC.z) + pd * bfhi(hD.z));
        a6 += (pa * bflo(hA.w) + pb * bflo(hB.w)) + (pc * bflo(hC.w) + pd * bflo(hD.w));
        a7 += (pa * bfhi(hA.w) + pb * bfhi(hB.w)) + (pc * bfhi(hC.w) + pd * bfhi(hD.w));
      }
#pragma unroll
      for (int off = 16; off <= 32; off <<= 1) {
        den += __shfl_xor(den, off);
        a0 += __shfl_xor(a0, off);
        a1 += __shfl_xor(a1, off);
        a2 += __shfl_xor(a2, off);
        a3 += __shfl_xor(a3, off);
        a4 += __shfl_xor(a4, off);
        a5 += __shfl_xor(a5, off);
        a6 += __shfl_xor(a6, off);
        a7 += __shfl_xor(a7, off);
      }
      if (qw == 0) {
        float rden = 1.f / (den + EPS);
        float4 bv0 = *(const float4*)&bias[8 * cl];
        float4 bv1 = *(const float4*)&bias[8 * cl + 4];
        float v0 = a0 * rden + bv0.x;
        float v1 = a1 * rden + bv0.y;
        float v2 = a2 * rden + bv0.z;
        float v3 = a3 * rden + bv0.w;
        float v4 = a4 * rden + bv1.x;
        float v5 = a5 * rden + bv1.y;
        float v6 = a6 * rden + bv1.z;
        float v7 = a7 * rden + bv1.w;
        v0 = v0 > 0.f ? v0 : expm1f(v0);
        v1 = v1 > 0.f ? v1 : expm1f(v1);
        v2 = v2 > 0.f ? v2 : expm1f(v2);
        v3 = v3 > 0.f ? v3 : expm1f(v3);
        v4 = v4 > 0.f ? v4 : expm1f(v4);
        v5 = v5 > 0.f ? v5 : expm1f(v5);
        v6 = v6 > 0.f ? v6 : expm1f(v6);
        v7 = v7 > 0.f ? v7 : expm1f(v7);
        uint4 o;
        o.x = pack2(v0, v1);
        o.y = pack2(v2, v3);
        o.z = pack2(v4, v5);
        o.w = pack2(v6, v7);
        *(uint4*)&((bf16*)outp)[(size_t)n * 128 + 8 * cl] = o;
      }
    }
  } else {
    for (int ln = wid; ln < nn; ln += 4) {
      const int n = nb0 + ln;
      const int start = B + escanp[ln] - histp[ln];
      const int end = B + escanp[ln];
      uint2 hv = *(const uint2*)&h[(size_t)n * 64 + 4 * cl];
      float g = qw ? 0.f : pself[n];
      float den = g;
      float a0 = g * bflo(hv.x), a1 = g * bfhi(hv.x);
      float a2 = g * bflo(hv.y), a3 = g * bfhi(hv.y);
      for (int j = start + 4 * qw; j < end; j += 16) {
        int4 ia = *(const int4*)&eidx[j];
        float4 pv = *(const float4*)&pcsr[j];
        uint2 hA = *(const uint2*)&h[(size_t)ia.x * 64 + 4 * cl];
        uint2 hB = *(const uint2*)&h[(size_t)ia.y * 64 + 4 * cl];
        uint2 hC = *(const uint2*)&h[(size_t)ia.z * 64 + 4 * cl];
        uint2 hD = *(const uint2*)&h[(size_t)ia.w * 64 + 4 * cl];
        den += (pv.x + pv.y) + (pv.z + pv.w);
        a0 += (pv.x * bflo(hA.x) + pv.y * bflo(hB.x)) + (pv.z * bflo(hC.x) + pv.w * bflo(hD.x));
        a1 += (pv.x * bfhi(hA.x) + pv.y * bfhi(hB.x)) + (pv.z * bfhi(hC.x) + pv.w * bfhi(hD.x));
        a2 += (pv.x * bflo(hA.y) + pv.y * bflo(hB.y)) + (pv.z * bflo(hC.y) + pv.w * bflo(hD.y));
        a3 += (pv.x * bfhi(hA.y) + pv.y * bfhi(hB.y)) + (pv.z * bfhi(hC.y) + pv.w * bfhi(hD.y));
      }
#pragma unroll
      for (int off = 16; off <= 32; off <<= 1) {
        den += __shfl_xor(den, off);
        a0 += __shfl_xor(a0, off);
        a1 += __shfl_xor(a1, off);
        a2 += __shfl_xor(a2, off);
        a3 += __shfl_xor(a3, off);
      }
      if (qw == 0) {
        float rden = 1.f / (den + EPS);
        float4 bv = *(const float4*)&bias[4 * cl];
        float v0 = a0 * rden + bv.x;
        float v1 = a1 * rden + bv.y;
        float v2 = a2 * rden + bv.z;
        float v3 = a3 * rden + bv.w;
        v0 = v0 > 0.f ? v0 : expm1f(v0);
        v1 = v1 > 0.f ? v1 : expm1f(v1);
        v2 = v2 > 0.f ? v2 : expm1f(v2);
        v3 = v3 > 0.f ? v3 : expm1f(v3);
        *(float4*)&((float*)outp)[(size_t)n * 64 + 4 * cl] = make_float4(v0, v1, v2, v3);
      }
    }
  }
}

extern "C" void kernel_launch(void* const* d_in, const int* in_sizes, int n_in,
                              void* d_out, int out_size, void* d_ws, size_t ws_size,
                              hipStream_t stream) {
  const float* x = (const float*)d_in[0];
  const int* ei1 = (const int*)d_in[1];
  const int* ei2 = (const int*)d_in[2];
  const float* W2 = (const float*)d_in[3];
  const float* as2 = (const float*)d_in[4];
  const float* ad2 = (const float*)d_in[5];
  const float* b2 = (const float*)d_in[6];
  const float* W1 = (const float*)d_in[7];
  const float* as1 = (const float*)d_in[8];
  const float* ad1 = (const float*)d_in[9];
  const float* b1 = (const float*)d_in[10];
  float* out = (float*)d_out;

  const int N = in_sizes[0] / 128;
  const int E1 = in_sizes[1] / 2;
  const int E2 = in_sizes[2] / 2;
  const int Emax = E1 > E2 ? E1 : E2;
  const size_t Ns = (size_t)N;

  const int nbuck = (N + BUCK_NODES - 1) / BUCK_NODES;  // 782 for N=100k (<= MAXBUCK)
  int lam = (Emax + nbuck - 1) / nbuck;
  int cap = lam + (lam >> 3) + 1408;  // variance slack + pad-to-8 worst case (7*128)
  cap = (cap + 63) & ~(int)63;
  const size_t NC = (size_t)nbuck * cap;

  float* ws = (float*)d_ws;
  size_t o = 0;
  unsigned short* Wb2 = (unsigned short*)(ws + o); o += 8192;   // 16384 bf16
  unsigned short* Wb1 = (unsigned short*)(ws + o); o += 4096;   // 8192 bf16
  float* asrc2 = ws + o;  o += 2 * Ns;
  float* adst2 = ws + o;  o += 2 * Ns;
  float* pself2 = ws + o; o += 2 * Ns;
  float* asrc1 = ws + o;  o += Ns;
  float* adst1 = ws + o;  o += Ns;
  float* pself1 = ws + o; o += Ns;
  int* gcur2 = (int*)(ws + o);   o += (size_t)nbuck;
  int* gcur1 = (int*)(ws + o);   o += (size_t)nbuck;
  o = (o + 7) & ~(size_t)7;
  int* slab2 = (int*)(ws + o);   o += NC;       // partition out -> in-place eidx (layer2)
  int* slab1 = (int*)(ws + o);   o += NC;       // partition out -> in-place eidx (layer1)
  o = (o + 7) & ~(size_t)7;
  float* pcsr = ws + o;          o += 2 * NC;   // l2: float2[NC] interleaved; l1: float[NC]
  o = (o + 7) & ~(size_t)7;
  bf16* h2 = (bf16*)(ws + o);    o += 64 * Ns;  // 128N bf16; h1 aliases (h2 dead after fused2)
  bf16* h1 = h2;
  bf16* hin1 = (bf16*)(ws + o);  o += 64 * Ns;  // 128N bf16

  const size_t smem2 = (size_t)cap * 4 + 4 * 256 * 4 + 16 + 2 * BUCK_NODES * 4 + 64;
  const size_t smem1 = (size_t)cap * 4 + 4 * 256 * 4 + 16 + 1 * BUCK_NODES * 4 + 64;

  const int nblk2 = (E2 + 4095) / 4096;
  const int nblk1 = (E1 + 4095) / 4096;

  // prep (convert W + zero bucket cursors)
  prep_kernel<<<(16384 + 8192 + 255) / 256, 256, 0, stream>>>(W2, Wb2, W1, Wb1, gcur2, 2 * nbuck);
  // both partitions in one launch
  partition_both_kernel<4096><<<nblk2 + nblk1, 256, 0, stream>>>(
      ei2, E2, gcur2, slab2, ei1, E1, gcur1, slab1, cap, nbuck, nblk2);

  // ---- layer 2: 128 -> [2 heads x 64], concat ----
  gemm_att_mfma<128, 2, true, float>
      <<<(N + 63) / 64, 256, 0, stream>>>(x, Wb2, as2, ad2, h2, asrc2, adst2, pself2, N);
  csr_gather_kernel<2, bf16><<<nbuck, 256, smem2, stream>>>(
      slab2, gcur2, cap, asrc2, adst2, pself2, pcsr, h2, b2, hin1, N);

  // ---- layer 1: 128 -> 64, single head ----
  gemm_att_mfma<64, 1, false, bf16>
      <<<(N + 63) / 64, 256, 0, stream>>>(hin1, Wb1, as1, ad1, h1, asrc1, adst1, pself1, N);
  csr_gather_kernel<1, float><<<nbuck, 256, smem1, stream>>>(
      slab1, gcur1, cap, asrc1, adst1, pself1, pcsr, h1, b1, out, N);
}

// Round 12
// 313.826 us; speedup vs baseline: 1.1496x; 1.1496x over previous
//
#include <hip/hip_runtime.h>
#include <hip/hip_bf16.h>
#include <math.h>

#define LRELU_SLOPE 0.2f
#define EPS 1e-16f
#define BUCK_SHIFT 8
#define BUCK_NODES 256
#define MAXBUCK 512

typedef __hip_bfloat16 bf16;
typedef __attribute__((ext_vector_type(8))) short bf16x8;
typedef __attribute__((ext_vector_type(4))) float f32x4;

__device__ inline float lrelu(float v) { return v > 0.f ? v : LRELU_SLOPE * v; }
__device__ inline float bflo(unsigned u) { return __uint_as_float(u << 16); }
__device__ inline float bfhi(unsigned u) { return __uint_as_float(u & 0xffff0000u); }
__device__ inline short f2bf(float f) {
  bf16 t = __float2bfloat16(f);
  return *reinterpret_cast<short*>(&t);
}
__device__ inline unsigned pack2(float lo, float hi) {
  return ((unsigned)(unsigned short)f2bf(hi) << 16) | (unsigned)(unsigned short)f2bf(lo);
}

// ---------------- prep: W f32 -> bf16 + zero gcur ----------------
__global__ void prep_kernel(const float* __restrict__ W2, unsigned short* __restrict__ Wb2,
                            const float* __restrict__ W1, unsigned short* __restrict__ Wb1,
                            int* __restrict__ gcur, int ngc) {
  int idx = blockIdx.x * blockDim.x + threadIdx.x;
  if (idx < ngc) gcur[idx] = 0;
  if (idx < 16384) {
    Wb2[idx] = (unsigned short)f2bf(W2[idx]);
  } else {
    int i = idx - 16384;
    if (i < 8192) Wb1[i] = (unsigned short)f2bf(W1[i]);
  }
}

// ---------------- bucket partition BOTH layers: edges -> per-bucket slabs (s<<8|d8) -------
template <int EPB>
__global__ __launch_bounds__(256) void partition_both_kernel(
    const int* __restrict__ ei2, int E2, int* __restrict__ gcur2, int* __restrict__ slab2,
    const int* __restrict__ ei1, int E1, int* __restrict__ gcur1, int* __restrict__ slab1,
    int cap, int nbuck, int nblk2) {
  __shared__ int cnt[MAXBUCK];
  __shared__ int sbase[MAXBUCK];
  const int tid = threadIdx.x;
  const bool l2 = (int)blockIdx.x < nblk2;
  const int bid = l2 ? blockIdx.x : blockIdx.x - nblk2;
  const int* ei = l2 ? ei2 : ei1;
  const int E = l2 ? E2 : E1;
  int* gcur = l2 ? gcur2 : gcur1;
  int* part = l2 ? slab2 : slab1;
  for (int t = tid; t < nbuck; t += 256) cnt[t] = 0;
  __syncthreads();
  const int e0 = bid * EPB;
  constexpr int KPT = EPB / 256;
  int sv[KPT], dv[KPT];
#pragma unroll
  for (int k = 0; k < KPT; k++) {
    int e = e0 + tid + k * 256;
    if (e < E) {
      sv[k] = ei[e];
      dv[k] = ei[E + e];
      atomicAdd(&cnt[dv[k] >> BUCK_SHIFT], 1);
    } else {
      dv[k] = -1;
    }
  }
  __syncthreads();
  for (int t = tid; t < nbuck; t += 256) {
    int c = cnt[t];
    if (c) sbase[t] = atomicAdd(&gcur[t], c);
    cnt[t] = 0;
  }
  __syncthreads();
#pragma unroll
  for (int k = 0; k < KPT; k++) {
    if (dv[k] >= 0) {
      int b = dv[k] >> BUCK_SHIFT;
      int pos = sbase[b] + atomicAdd(&cnt[b], 1);
      if (pos < cap) part[(size_t)b * cap + pos] = (sv[k] << 8) | (dv[k] & (BUCK_NODES - 1));
    }
  }
}

// ---------------- per-bucket CSR build, IN-PLACE (slab re-written as eidx) ----------------
// Stages the whole slab in LDS before writing; pad-to-8 rows; interleaved float2 pcsr (H=2).
template <int H>
__global__ __launch_bounds__(256) void csr_build_kernel(
    int* __restrict__ slab, const int* __restrict__ gcur, int cap,
    const float* __restrict__ asrc, const float* __restrict__ adst, float* __restrict__ pcsr,
    int* __restrict__ rowbeg, int* __restrict__ rowend, int N) {
  extern __shared__ char smem[];
  int* s_sd = (int*)smem;              // [cap] packed (s<<8|d8)
  int* hist = (int*)(s_sd + cap);      // [256]
  int* histp = hist + 256;             // [256] padded counts
  int* escanp = histp + 256;           // [256] inclusive scan of histp
  int* cur = escanp + 256;             // [256]
  int* wtot = cur + 256;               // [4]
  float* s_ad = (float*)(wtot + 4);    // [H*256]

  const int b = blockIdx.x;
  const int tid = threadIdx.x;
  const int lane = tid & 63;
  const int wid = tid >> 6;
  const int nb0 = b << BUCK_SHIFT;
  const int nn = min(BUCK_NODES, N - nb0);
  const int cnt = min(gcur[b], cap - 7 * BUCK_NODES);  // room for worst-case padding
  const int B = b * cap;
  int* eidx = slab;  // in-place: all reads of slab complete (staged in LDS) before writes

  hist[tid] = 0;
  cur[tid] = 0;
  for (int t = tid; t < nn * H; t += 256) s_ad[t] = adst[(size_t)nb0 * H + t];
  __syncthreads();
  for (int i = tid; i < cnt; i += 256) {
    int pr = slab[(size_t)B + i];
    s_sd[i] = pr;
    atomicAdd(&hist[pr & (BUCK_NODES - 1)], 1);
  }
  __syncthreads();
  // inclusive scan of padded counts: wave shfl_up scan + cross-wave fixup (2 barriers)
  const int h0 = hist[tid];
  const int hp = (h0 + 7) & ~7;
  histp[tid] = hp;
  int inc = hp;
#pragma unroll
  for (int off = 1; off < 64; off <<= 1) {
    int t = __shfl_up(inc, off);
    if (lane >= off) inc += t;
  }
  if (lane == 63) wtot[wid] = inc;
  __syncthreads();
  int base = 0;
  for (int w = 0; w < wid; w++) base += wtot[w];
  escanp[tid] = inc + base;
  if (tid < nn) {
    rowbeg[nb0 + tid] = B + inc + base - hp;
    rowend[nb0 + tid] = B + inc + base;
  }
  __syncthreads();
  // scatter real edges (writes into slab; all slab reads already done)
  for (int i = tid; i < cnt; i += 256) {
    int pr = s_sd[i];
    int d8 = pr & (BUCK_NODES - 1);
    int s = pr >> 8;
    int slot = B + (escanp[d8] - histp[d8]) + atomicAdd(&cur[d8], 1);
    eidx[slot] = s;
    if constexpr (H == 2) {
      float2 a = *(const float2*)&asrc[2 * (size_t)s];
      float2 ad = *(const float2*)&s_ad[2 * d8];
      float2 pv;
      pv.x = __expf(lrelu(a.x + ad.x));
      pv.y = __expf(lrelu(a.y + ad.y));
      *(float2*)&pcsr[2 * (size_t)slot] = pv;
    } else {
      pcsr[slot] = __expf(lrelu(asrc[s] + s_ad[d8]));
    }
  }
  // pad slots: src = dst node (valid row, L1-hot in gather), p = 0 -> contributes nothing
  if (tid < nn) {
    int pb = B + escanp[tid] - histp[tid];
    for (int k = h0; k < hp; k++) {
      eidx[pb + k] = nb0 + tid;
      if constexpr (H == 2) {
        *(float2*)&pcsr[2 * (size_t)(pb + k)] = make_float2(0.f, 0.f);
      } else {
        pcsr[pb + k] = 0.f;
      }
    }
  }
}

// ---------------- MFMA GEMM (h = x @ W^T, bf16) + fused att dots + self-loop p ------------
// f32 input is converted to bf16 (RNE) on the fly: single-MFMA path. W already bf16.
template <int M, int H, typename Tin>
__global__ __launch_bounds__(256) void gemm_att_mfma(
    const Tin* __restrict__ x, const unsigned short* __restrict__ Wb,
    const float* __restrict__ atts, const float* __restrict__ attd, bf16* __restrict__ h,
    float* __restrict__ asrc, float* __restrict__ adst, float* __restrict__ pself, int N) {
  constexpr int K = 128;
  constexpr int NF = M / 16;
  const int wid = threadIdx.x >> 6;
  const int lane = threadIdx.x & 63;
  const int r0 = blockIdx.x * 64 + wid * 16;
  if (r0 >= N) return;
  const int colb = lane & 15;
  const int kgrp = lane >> 4;
  const size_t arow = (size_t)min(r0 + colb, N - 1);

  f32x4 acc[NF];
#pragma unroll
  for (int f = 0; f < NF; f++) acc[f] = (f32x4){0.f, 0.f, 0.f, 0.f};

#pragma unroll
  for (int k0 = 0; k0 < K; k0 += 32) {
    const int kb = k0 + kgrp * 8;
    bf16x8 ahi;
    if constexpr (sizeof(Tin) == 4) {
      const float* xp = (const float*)x + arow * K + kb;
      float4 l0 = *(const float4*)xp;
      float4 l1 = *(const float4*)(xp + 4);
      ahi[0] = f2bf(l0.x); ahi[1] = f2bf(l0.y);
      ahi[2] = f2bf(l0.z); ahi[3] = f2bf(l0.w);
      ahi[4] = f2bf(l1.x); ahi[5] = f2bf(l1.y);
      ahi[6] = f2bf(l1.z); ahi[7] = f2bf(l1.w);
    } else {
      ahi = *(const bf16x8*)((const unsigned short*)x + arow * K + kb);
    }
#pragma unroll
    for (int f = 0; f < NF; f++) {
      bf16x8 b = *(const bf16x8*)(Wb + (size_t)(f * 16 + colb) * K + kb);
      acc[f] = __builtin_amdgcn_mfma_f32_16x16x32_bf16(ahi, b, acc[f], 0, 0, 0);
    }
  }

#pragma unroll
  for (int r = 0; r < 4; r++) {
    const int row = r0 + kgrp * 4 + r;
    const bool ok = row < N;
    float s0 = 0.f, d0 = 0.f, s1 = 0.f, d1 = 0.f;
#pragma unroll
    for (int f = 0; f < NF; f++) {
      float v = acc[f][r];
      int c = f * 16 + colb;
      if (ok) h[(size_t)row * M + c] = __float2bfloat16(v);
      float av = atts[c], dv = attd[c];
      if (H == 2 && f >= NF / 2) {
        s1 += v * av;
        d1 += v * dv;
      } else {
        s0 += v * av;
        d0 += v * dv;
      }
    }
#pragma unroll
    for (int off = 1; off < 16; off <<= 1) {
      s0 += __shfl_xor(s0, off);
      d0 += __shfl_xor(d0, off);
      if (H == 2) {
        s1 += __shfl_xor(s1, off);
        d1 += __shfl_xor(d1, off);
      }
    }
    if (ok && colb == 0) {
      if (H == 2) {
        asrc[2 * (size_t)row] = s0;
        asrc[2 * (size_t)row + 1] = s1;
        adst[2 * (size_t)row] = d0;
        adst[2 * (size_t)row + 1] = d1;
        *(float2*)&pself[2 * (size_t)row] =
            make_float2(__expf(lrelu(s0 + d0)), __expf(lrelu(s1 + d1)));
      } else {
        asrc[row] = s0;
        adst[row] = d0;
        pself[row] = __expf(lrelu(s0 + d0));
      }
    }
  }
}

// ---------------- gather, layer2: quarter-wave per edge-quad, 16 rows in flight ----------
// 16 lanes cover a 256 B row (uint4 each); quarter qw walks quads j = start+4*qw step 16.
__global__ void gather2_kernel(const bf16* __restrict__ h, const float* __restrict__ pself,
                               const int* __restrict__ rowbeg, const int* __restrict__ rowend,
                               const int* __restrict__ eidx, const float* __restrict__ pcsr,
                               const float* __restrict__ bias, bf16* __restrict__ outp, int N) {
  long long gt = (long long)blockIdx.x * blockDim.x + threadIdx.x;
  int n = (int)(gt >> 6);
  int lane = threadIdx.x & 63;
  if (n >= N) return;
  const int qw = lane >> 4;
  const int cl = lane & 15;  // cols 8*cl .. 8*cl+7 ; cl<8 -> head0
  const bool head0 = cl < 8;
  int start = rowbeg[n];
  int end = rowend[n];
  const float2 ps = *(const float2*)&pself[2 * (size_t)n];
  float g = qw ? 0.f : (head0 ? ps.x : ps.y);  // self-loop counted once (qw 0)
  uint4 hv = *(const uint4*)&h[(size_t)n * 128 + 8 * cl];
  float den = g;
  float a0 = g * bflo(hv.x), a1 = g * bfhi(hv.x);
  float a2 = g * bflo(hv.y), a3 = g * bfhi(hv.y);
  float a4 = g * bflo(hv.z), a5 = g * bfhi(hv.z);
  float a6 = g * bflo(hv.w), a7 = g * bfhi(hv.w);
  for (int j = start + 4 * qw; j < end; j += 16) {
    int4 ia = *(const int4*)&eidx[j];
    float4 q0 = *(const float4*)&pcsr[2 * (size_t)j];      // e0(h0,h1) e1(h0,h1)
    float4 q1 = *(const float4*)&pcsr[2 * (size_t)j + 4];  // e2, e3
    uint4 hA = *(const uint4*)&h[(size_t)ia.x * 128 + 8 * cl];
    uint4 hB = *(const uint4*)&h[(size_t)ia.y * 128 + 8 * cl];
    uint4 hC = *(const uint4*)&h[(size_t)ia.z * 128 + 8 * cl];
    uint4 hD = *(const uint4*)&h[(size_t)ia.w * 128 + 8 * cl];
    float pa = head0 ? q0.x : q0.y;
    float pb = head0 ? q0.z : q0.w;
    float pc = head0 ? q1.x : q1.y;
    float pd = head0 ? q1.z : q1.w;
    den += (pa + pb) + (pc + pd);
    a0 += (pa * bflo(hA.x) + pb * bflo(hB.x)) + (pc * bflo(hC.x) + pd * bflo(hD.x));
    a1 += (pa * bfhi(hA.x) + pb * bfhi(hB.x)) + (pc * bfhi(hC.x) + pd * bfhi(hD.x));
    a2 += (pa * bflo(hA.y) + pb * bflo(hB.y)) + (pc * bflo(hC.y) + pd * bflo(hD.y));
    a3 += (pa * bfhi(hA.y) + pb * bfhi(hB.y)) + (pc * bfhi(hC.y) + pd * bfhi(hD.y));
    a4 += (pa * bflo(hA.z) + pb * bflo(hB.z)) + (pc * bflo(hC.z) + pd * bflo(hD.z));
    a5 += (pa * bfhi(hA.z) + pb * bfhi(hB.z)) + (pc * bfhi(hC.z) + pd * bfhi(hD.z));
    a6 += (pa * bflo(hA.w) + pb * bflo(hB.w)) + (pc * bflo(hC.w) + pd * bflo(hD.w));
    a7 += (pa * bfhi(hA.w) + pb * bfhi(hB.w)) + (pc * bfhi(hC.w) + pd * bfhi(hD.w));
  }
#pragma unroll
  for (int off = 16; off <= 32; off <<= 1) {
    den += __shfl_xor(den, off);
    a0 += __shfl_xor(a0, off);
    a1 += __shfl_xor(a1, off);
    a2 += __shfl_xor(a2, off);
    a3 += __shfl_xor(a3, off);
    a4 += __shfl_xor(a4, off);
    a5 += __shfl_xor(a5, off);
    a6 += __shfl_xor(a6, off);
    a7 += __shfl_xor(a7, off);
  }
  if (qw == 0) {
    float rden = 1.f / (den + EPS);
    float4 bv0 = *(const float4*)&bias[8 * cl];
    float4 bv1 = *(const float4*)&bias[8 * cl + 4];
    float v0 = a0 * rden + bv0.x;
    float v1 = a1 * rden + bv0.y;
    float v2 = a2 * rden + bv0.z;
    float v3 = a3 * rden + bv0.w;
    float v4 = a4 * rden + bv1.x;
    float v5 = a5 * rden + bv1.y;
    float v6 = a6 * rden + bv1.z;
    float v7 = a7 * rden + bv1.w;
    v0 = v0 > 0.f ? v0 : expm1f(v0);
    v1 = v1 > 0.f ? v1 : expm1f(v1);
    v2 = v2 > 0.f ? v2 : expm1f(v2);
    v3 = v3 > 0.f ? v3 : expm1f(v3);
    v4 = v4 > 0.f ? v4 : expm1f(v4);
    v5 = v5 > 0.f ? v5 : expm1f(v5);
    v6 = v6 > 0.f ? v6 : expm1f(v6);
    v7 = v7 > 0.f ? v7 : expm1f(v7);
    uint4 o;
    o.x = pack2(v0, v1);
    o.y = pack2(v2, v3);
    o.z = pack2(v4, v5);
    o.w = pack2(v6, v7);
    *(uint4*)&outp[(size_t)n * 128 + 8 * cl] = o;
  }
}

// ---------------- gather, layer1: quarter-wave per edge-quad, 16 rows in flight ----------
// 16 lanes cover a 128 B row (uint2 each = 4 cols).
__global__ void gather1_kernel(const bf16* __restrict__ h, const float* __restrict__ pself,
                               const int* __restrict__ rowbeg, const int* __restrict__ rowend,
                               const int* __restrict__ eidx, const float* __restrict__ pcsr,
                               const float* __restrict__ bias, float* __restrict__ outp, int N) {
  long long gt = (long long)blockIdx.x * blockDim.x + threadIdx.x;
  int n = (int)(gt >> 6);
  int lane = threadIdx.x & 63;
  if (n >= N) return;
  const int qw = lane >> 4;
  const int cl = lane & 15;  // cols 4*cl .. 4*cl+3
  int start = rowbeg[n];
  int end = rowend[n];
  uint2 hv = *(const uint2*)&h[(size_t)n * 64 + 4 * cl];
  float g = qw ? 0.f : pself[n];  // self-loop counted once (qw 0)
  float den = g;
  float a0 = g * bflo(hv.x), a1 = g * bfhi(hv.x);
  float a2 = g * bflo(hv.y), a3 = g * bfhi(hv.y);
  for (int j = start + 4 * qw; j < end; j += 16) {
    int4 ia = *(const int4*)&eidx[j];
    float4 pv = *(const float4*)&pcsr[j];
    uint2 hA = *(const uint2*)&h[(size_t)ia.x * 64 + 4 * cl];
    uint2 hB = *(const uint2*)&h[(size_t)ia.y * 64 + 4 * cl];
    uint2 hC = *(const uint2*)&h[(size_t)ia.z * 64 + 4 * cl];
    uint2 hD = *(const uint2*)&h[(size_t)ia.w * 64 + 4 * cl];
    den += (pv.x + pv.y) + (pv.z + pv.w);
    a0 += (pv.x * bflo(hA.x) + pv.y * bflo(hB.x)) + (pv.z * bflo(hC.x) + pv.w * bflo(hD.x));
    a1 += (pv.x * bfhi(hA.x) + pv.y * bfhi(hB.x)) + (pv.z * bfhi(hC.x) + pv.w * bfhi(hD.x));
    a2 += (pv.x * bflo(hA.y) + pv.y * bflo(hB.y)) + (pv.z * bflo(hC.y) + pv.w * bflo(hD.y));
    a3 += (pv.x * bfhi(hA.y) + pv.y * bfhi(hB.y)) + (pv.z * bfhi(hC.y) + pv.w * bfhi(hD.y));
  }
#pragma unroll
  for (int off = 16; off <= 32; off <<= 1) {
    den += __shfl_xor(den, off);
    a0 += __shfl_xor(a0, off);
    a1 += __shfl_xor(a1, off);
    a2 += __shfl_xor(a2, off);
    a3 += __shfl_xor(a3, off);
  }
  if (qw == 0) {
    float rden = 1.f / (den + EPS);
    float4 bv = *(const float4*)&bias[4 * cl];
    float v0 = a0 * rden + bv.x;
    float v1 = a1 * rden + bv.y;
    float v2 = a2 * rden + bv.z;
    float v3 = a3 * rden + bv.w;
    v0 = v0 > 0.f ? v0 : expm1f(v0);
    v1 = v1 > 0.f ? v1 : expm1f(v1);
    v2 = v2 > 0.f ? v2 : expm1f(v2);
    v3 = v3 > 0.f ? v3 : expm1f(v3);
    *(float4*)&outp[(size_t)n * 64 + 4 * cl] = make_float4(v0, v1, v2, v3);
  }
}

extern "C" void kernel_launch(void* const* d_in, const int* in_sizes, int n_in,
                              void* d_out, int out_size, void* d_ws, size_t ws_size,
                              hipStream_t stream) {
  const float* x = (const float*)d_in[0];
  const int* ei1 = (const int*)d_in[1];
  const int* ei2 = (const int*)d_in[2];
  const float* W2 = (const float*)d_in[3];
  const float* as2 = (const float*)d_in[4];
  const float* ad2 = (const float*)d_in[5];
  const float* b2 = (const float*)d_in[6];
  const float* W1 = (const float*)d_in[7];
  const float* as1 = (const float*)d_in[8];
  const float* ad1 = (const float*)d_in[9];
  const float* b1 = (const float*)d_in[10];
  float* out = (float*)d_out;

  const int N = in_sizes[0] / 128;
  const int E1 = in_sizes[1] / 2;
  const int E2 = in_sizes[2] / 2;
  const int Emax = E1 > E2 ? E1 : E2;
  const size_t Ns = (size_t)N;

  const int nbuck = (N + BUCK_NODES - 1) / BUCK_NODES;  // 391 for N=100k (<= MAXBUCK)
  int lam = (Emax + nbuck - 1) / nbuck;
  int cap = lam + (lam >> 2) + 2048;  // slack: count variance + pad-to-8 worst case
  cap = (cap + 255) & ~(int)255;
  const size_t NC = (size_t)nbuck * cap;

  float* ws = (float*)d_ws;
  size_t o = 0;
  unsigned short* Wb2 = (unsigned short*)(ws + o); o += 8192;   // 16384 bf16
  unsigned short* Wb1 = (unsigned short*)(ws + o); o += 4096;   // 8192 bf16
  float* asrc2 = ws + o;  o += 2 * Ns;
  float* adst2 = ws + o;  o += 2 * Ns;
  float* pself2 = ws + o; o += 2 * Ns;
  float* asrc1 = ws + o;  o += Ns;
  float* adst1 = ws + o;  o += Ns;
  float* pself1 = ws + o; o += Ns;
  int* gcur2 = (int*)(ws + o);   o += (size_t)nbuck;
  int* gcur1 = (int*)(ws + o);   o += (size_t)nbuck;
  int* rowbeg2 = (int*)(ws + o); o += Ns;
  int* rowend2 = (int*)(ws + o); o += Ns;
  int* rowbeg1 = (int*)(ws + o); o += Ns;
  int* rowend1 = (int*)(ws + o); o += Ns;
  o = (o + 7) & ~(size_t)7;
  int* slab2 = (int*)(ws + o);   o += NC;       // partition out -> in-place eidx (layer2)
  int* slab1 = (int*)(ws + o);   o += NC;       // partition out -> in-place eidx (layer1)
  o = (o + 7) & ~(size_t)7;
  float* pcsr = ws + o;          o += 2 * NC;   // l2: float2[NC] interleaved; l1: float[NC]
  o = (o + 7) & ~(size_t)7;
  bf16* h2 = (bf16*)(ws + o);    o += 64 * Ns;  // 128N bf16; h1 aliases (h2 dead after gather2)
  bf16* h1 = h2;
  bf16* hin1 = (bf16*)(ws + o);  o += 64 * Ns;  // 128N bf16

  const size_t smem2 = (size_t)cap * 4 + 4 * 256 * 4 + 16 + 2 * 256 * 4 + 64;
  const size_t smem1 = (size_t)cap * 4 + 4 * 256 * 4 + 16 + 1 * 256 * 4 + 64;

  const int nblk2 = (E2 + 4095) / 4096;
  const int nblk1 = (E1 + 4095) / 4096;

  // prep (convert W + zero bucket cursors)
  prep_kernel<<<(16384 + 8192 + 255) / 256, 256, 0, stream>>>(W2, Wb2, W1, Wb1, gcur2, 2 * nbuck);
  // both partitions in one launch
  partition_both_kernel<4096><<<nblk2 + nblk1, 256, 0, stream>>>(
      ei2, E2, gcur2, slab2, ei1, E1, gcur1, slab1, cap, nbuck, nblk2);

  // ---- layer 2: 128 -> [2 heads x 64], concat ----
  gemm_att_mfma<128, 2, float>
      <<<(N + 63) / 64, 256, 0, stream>>>(x, Wb2, as2, ad2, h2, asrc2, adst2, pself2, N);
  csr_build_kernel<2><<<nbuck, 256, smem2, stream>>>(slab2, gcur2, cap, asrc2, adst2, pcsr,
                                                     rowbeg2, rowend2, N);
  gather2_kernel<<<(N + 3) / 4, 256, 0, stream>>>(h2, pself2, rowbeg2, rowend2, slab2, pcsr,
                                                  b2, hin1, N);

  // ---- layer 1: 128 -> 64, single head ----
  gemm_att_mfma<64, 1, bf16>
      <<<(N + 63) / 64, 256, 0, stream>>>(hin1, Wb1, as1, ad1, h1, asrc1, adst1, pself1, N);
  csr_build_kernel<1><<<nbuck, 256, smem1, stream>>>(slab1, gcur1, cap, asrc1, adst1, pcsr,
                                                     rowbeg1, rowend1, N);
  gather1_kernel<<<(N + 3) / 4, 256, 0, stream>>>(h1, pself1, rowbeg1, rowend1, slab1, pcsr,
                                                  b1, out, N);
}